// Round 9
// baseline (186.233 us; speedup 1.0000x reference)
//
#include <hip/hip_runtime.h>
#include <math.h>

// Problem constants: V=50000, D=100, B=16, S=128, U=100, L=2
#define NB 16
#define SS 128
#define DD 100
#define KK 100
#define T_TILE 8
#define NTILES 16
#define NT 512          // 8 waves = 4 d-quarters (h) x 2 pos-groups (g)

__device__ __forceinline__ float dot4(const float4 a, const float4 b) {
  return a.x * b.x + a.y * b.y + a.z * b.z + a.w * b.w;
}
// exact x/25 for x < 2560
__device__ __forceinline__ int div25(int x) { return (x * 10486) >> 18; }

// ---------------------------------------------------------------------------
// V staging, reg half (coalesced linear 40KB) and LDS half (bank-spread).
// chunk (k, su) -> f4 idx su*100 + (k&1)*50 + ((k>>1)+su)%50  (R8-proven)
// ---------------------------------------------------------------------------
__device__ __forceinline__ void issue5(const float* __restrict__ gv, int tid,
                                       float4 (&gl)[5]) {
#pragma unroll
  for (int r = 0; r < 5; ++r) {
    const int g = tid + 512 * r;
    if (g < 2500) gl[r] = *(const float4*)(gv + 4 * g);
  }
}
__device__ __forceinline__ void write5(float* __restrict__ vbuf, int tid,
                                       const float4 (&gl)[5]) {
#pragma unroll
  for (int r = 0; r < 5; ++r) {
    const int g = tid + 512 * r;
    if (g < 2500) {
      const int k = div25(g), su = g - 25 * k;
      int col = (k >> 1) + su; if (col >= 50) col -= 50;
      ((float4*)vbuf)[su * 100 + (k & 1) * 50 + col] = gl[r];
    }
  }
}

// ---------------------------------------------------------------------------
// One projection stage. MODE 0: complex x; MODE 1: real x.
// CM 1: m = |Y|^2*iv ; CM 2: m = |w0 Y(p)+w1 Y(p+1)|^2*iv ; CM 3: y3 = Y raw.
// Lane owns k-pair (2kp,2kp+1); wave (h,g): d-chunks [O,O+nu), positions 6g+e.
// bufR/bufI: r,i parts staged at stage top (loads issued a full stage ago ->
// no vmcnt stall). Next stage: part r issued during FMA, part i during combine.
// ---------------------------------------------------------------------------
template<int MODE, int CM>
__device__ __forceinline__ void do_stage(
    float* __restrict__ bufR, float* __restrict__ bufI,
    float4 (&glr)[5], float4 (&gli)[5],
    const float* __restrict__ gnextR, const float* __restrict__ gnextI,
    const float* __restrict__ xR, const float* __restrict__ xI,
    float* __restrict__ outp, float* __restrict__ invvnU,
    const float* __restrict__ es, const float* __restrict__ sc,
    int O, int nu, int pmaxF, int pmaxC,
    int tid, int h, int g, int kp, bool act, int t0)
{
  float4* partlp = (float4*)bufR;                    // [4][11][50] overlay
  float2* nrmhp  = (float2*)(bufR + 8800);           // [4][50]
  float4 Vr0[7], Vr1[7], Vi0[7], Vi1[7];
  float n0 = 0.f, n1 = 0.f;

  // 1. both parts regs -> LDS (values loaded a full stage ago)
  write5(bufR, tid, glr);
  write5(bufI, tid, gli);
  __syncthreads();

  // 2. reg-fill both parts; issue next stage's part-r during FMA
#pragma unroll
  for (int U = 0; U < 7; ++U) if (U < nu) {
    const int su = O + U;
    int col = kp + su; if (col >= 50) col -= 50;
    const float4* r4 = (const float4*)bufR + su * 100 + col;
    const float4* i4 = (const float4*)bufI + su * 100 + col;
    Vr0[U] = r4[0];  Vr1[U] = r4[50];
    Vi0[U] = i4[0];  Vi1[U] = i4[50];
    n0 += dot4(Vr0[U], Vr0[U]) + dot4(Vi0[U], Vi0[U]);
    n1 += dot4(Vr1[U], Vr1[U]) + dot4(Vi1[U], Vi1[U]);
  }
  if (gnextR) issue5(gnextR, tid, glr);

  // 3. FMA: x uniform-broadcast from LDS, V in regs
  float ar[6][2] = {{0}}, ai[6][2] = {{0}};
#pragma unroll
  for (int U = 0; U < 7; ++U) if (U < nu) {
    const int du = 4 * (O + U);
#pragma unroll
    for (int e = 0; e < 6; ++e) {
      const int p = 6 * g + e;
      if (p <= pmaxF) {
        const float4 xr = *(const float4*)(xR + p * DD + du);
        if (MODE == 0) {
          const float4 xi = *(const float4*)(xI + p * DD + du);
          ar[e][0] += dot4(Vr0[U], xr) + dot4(Vi0[U], xi);
          ai[e][0] += dot4(Vr0[U], xi) - dot4(Vi0[U], xr);
          ar[e][1] += dot4(Vr1[U], xr) + dot4(Vi1[U], xi);
          ai[e][1] += dot4(Vr1[U], xi) - dot4(Vi1[U], xr);
        } else {
          ar[e][0] += dot4(Vr0[U], xr);
          ai[e][0] += dot4(Vi0[U], xr);
          ar[e][1] += dot4(Vr1[U], xr);
          ai[e][1] += dot4(Vi1[U], xr);
        }
      }
    }
  }
  __syncthreads();    // bufR/bufI dead; partl overlay live

  // 4. partials; issue next stage's part-i during combine window
  if (act) {
#pragma unroll
    for (int e = 0; e < 6; ++e) {
      const int p = 6 * g + e;
      if (p <= pmaxF)
        partlp[(h * 11 + p) * 50 + kp] =
            make_float4(ar[e][0], ai[e][0], ar[e][1], ai[e][1]);
    }
    if (g == 0) nrmhp[h * 50 + kp] = make_float2(n0, n1);
  }
  if (gnextI) issue5(gnextI, tid, gli);
  __syncthreads();

  // 5. combine (h==0 waves; g splits p)
  if (h == 0 && act) {
    const float2 q0 = nrmhp[kp], q1 = nrmhp[50 + kp],
                 q2 = nrmhp[100 + kp], q3 = nrmhp[150 + kp];
    const float iv0 = 1.f / (q0.x + q1.x + q2.x + q3.x);
    const float iv1 = 1.f / (q0.y + q1.y + q2.y + q3.y);
#pragma unroll
    for (int e = 0; e < 6; ++e) {
      const int p = 6 * g + e;
      if (p <= pmaxC) {
        float4 s = partlp[p * 50 + kp];
        {
          const float4 b1 = partlp[(11 + p) * 50 + kp];
          const float4 b2 = partlp[(22 + p) * 50 + kp];
          const float4 b3 = partlp[(33 + p) * 50 + kp];
          s.x += b1.x + b2.x + b3.x;  s.y += b1.y + b2.y + b3.y;
          s.z += b1.z + b2.z + b3.z;  s.w += b1.w + b2.w + b3.w;
        }
        if (CM == 1) {
          *(float2*)(outp + p * DD + 2 * kp) =
              make_float2((s.x * s.x + s.y * s.y) * iv0,
                          (s.z * s.z + s.w * s.w) * iv1);
        } else if (CM == 2) {
          float4 u = partlp[(p + 1) * 50 + kp];
          const float4 c1 = partlp[(12 + p) * 50 + kp];
          const float4 c2 = partlp[(23 + p) * 50 + kp];
          const float4 c3 = partlp[(34 + p) * 50 + kp];
          u.x += c1.x + c2.x + c3.x;  u.y += c1.y + c2.y + c3.y;
          u.z += c1.z + c2.z + c3.z;  u.w += c1.w + c2.w + c3.w;
          const int t = t0 + p;
          const float w0 = es[t] / sc[0];
          const float w1 = es[t + 1] / sc[1];     // es zero-padded past SS
          const float r0 = w0 * s.x + w1 * u.x, i0 = w0 * s.y + w1 * u.y;
          const float r1 = w0 * s.z + w1 * u.z, i1 = w0 * s.w + w1 * u.w;
          *(float2*)(outp + p * DD + 2 * kp) =
              make_float2((r0 * r0 + i0 * i0) * iv0, (r1 * r1 + i1 * i1) * iv1);
        } else {
          *(float4*)(outp + p * 2 * DD + 4 * kp) = s;   // y3 [p][k] float2
        }
      }
    }
    if (CM == 3 && g == 0) { invvnU[2 * kp] = iv0; invvnU[2 * kp + 1] = iv1; }
  }
  __syncthreads();
}

// ---------------------------------------------------------------------------
// k_phi: gather + norms + phi, ONCE per position (kills per-tile re-gather).
// 32 blocks x 512 threads; 8 threads per position.
// ---------------------------------------------------------------------------
__global__ __launch_bounds__(512) void k_phi(
    const int* __restrict__ seq,
    const float* __restrict__ ampT, const float* __restrict__ phT,
    float* __restrict__ phR, float* __restrict__ phI,
    float* __restrict__ es_g, float* __restrict__ wnl_g)
{
  const int tid = threadIdx.x;
  const int P   = blockIdx.x * 64 + (tid >> 3);   // global position, < 2048
  const int qq  = tid & 7;
  const int row = seq[P];
  const float* ap = ampT + (long)row * DD;
  const float* pp = phT  + (long)row * DD;

  float s = 0.f;
  float4 a4[4];
#pragma unroll
  for (int i = 0; i < 4; ++i) {
    const int j = qq + 8 * i;
    if (j < 25) { a4[i] = *(const float4*)(ap + 4 * j); s += dot4(a4[i], a4[i]); }
  }
  s += __shfl_xor(s, 1);
  s += __shfl_xor(s, 2);
  s += __shfl_xor(s, 4);
  const float n = sqrtf(s);
  if (qq == 0) { wnl_g[P] = n; es_g[P] = expf(n); }
  const float inv = 1.0f / n;
#pragma unroll
  for (int i = 0; i < 4; ++i) {
    const int j = qq + 8 * i;
    if (j < 25) {
      const float4 p4 = *(const float4*)(pp + 4 * j);
      float4 orr, oii; float sv, cv;
      sincosf(p4.x, &sv, &cv); orr.x = a4[i].x * inv * cv; oii.x = a4[i].x * inv * sv;
      sincosf(p4.y, &sv, &cv); orr.y = a4[i].y * inv * cv; oii.y = a4[i].y * inv * sv;
      sincosf(p4.z, &sv, &cv); orr.z = a4[i].z * inv * cv; oii.z = a4[i].z * inv * sv;
      sincosf(p4.w, &sv, &cv); orr.w = a4[i].w * inv * cv; oii.w = a4[i].w * inv * sv;
      *(float4*)(phR + P * DD + 4 * j) = orr;
      *(float4*)(phI + P * DD + 4 * j) = oii;
    }
  }
}

// ---------------------------------------------------------------------------
__global__ __launch_bounds__(NT) void k_fused(
    const float* __restrict__ phR, const float* __restrict__ phI,
    const float* __restrict__ es_g, const float* __restrict__ wnl_g,
    const float* __restrict__ pkr, const float* __restrict__ pki,
    const float* __restrict__ mkr, const float* __restrict__ mki,
    float* __restrict__ partg)
{
  __shared__ __align__(16) float bufR[10000];   // 40 KB (partl/nrmh overlay)
  __shared__ __align__(16) float bufI[10000];   // 40 KB
  __shared__ __align__(16) float xb[2208];      // phi_r|phi_i -> m1|m2 -> y3
  __shared__ float es[SS + 8], wnl[SS], invvnU[KK], sc[3], redw[2];

  const int tid  = threadIdx.x;
  const int lane = tid & 63;
  const int wid  = tid >> 6;
  const int h    = wid & 3;
  const int g    = wid >> 2;
  const bool act = lane < 50;
  const int kp   = act ? lane : 49;
  const int bt   = blockIdx.x;
  const int b    = bt >> 4;
  const int t0   = (bt & 15) * T_TILE;
  const int O    = (h == 0) ? 0 : 1 + 6 * h;    // 0,7,13,19
  const int nu   = (h == 0) ? 7 : 6;

  float4 glr[5], gli[5];
  issue5(pkr, tid, glr);                        // stage-1 parts, issued first
  issue5(pki, tid, gli);

  // --- prologue: per-batch norm state + linear phi halo ---
  if (tid < SS) { es[tid] = es_g[b * SS + tid]; wnl[tid] = wnl_g[b * SS + tid]; }
  if (tid >= NT - 8) es[SS + tid - (NT - 8)] = 0.f;
  __syncthreads();
  if (tid < SS) {
    float v = es[tid];
#pragma unroll
    for (int m = 32; m; m >>= 1) v += __shfl_xor(v, m);
    if ((tid & 63) == 0) redw[tid >> 6] = v;
  }
  {
    const float* pr0 = phR + b * (SS * DD) + t0 * DD;
    const float* pi0 = phI + b * (SS * DD) + t0 * DD;
    const int lim = SS * DD - t0 * DD;          // valid floats in this batch
#pragma unroll
    for (int r = 0; r < 3; ++r) {
      const int e2 = tid + 512 * r;
      if (e2 < 1100) {
        const bool ok = e2 < lim;
        xb[e2]        = ok ? pr0[e2] : 0.f;
        xb[1100 + e2] = ok ? pi0[e2] : 0.f;
      }
    }
  }
  __syncthreads();
  if (tid == 0) {
    const float E = redw[0] + redw[1];
    sc[0] = E; sc[1] = E - es[0] + 1.f; sc[2] = E - es[0] - es[1] + 2.f;
  }
  // sc first consumed at stage-2 combine (many barriers later)

  // --- stage 1: m1 = |<v0, phi>|^2 * iv  -> xb[0..1100) ---
  do_stage<0, 1>(bufR, bufI, glr, gli, pkr + DD * DD, pki + DD * DD,
                 xb, xb + 1100, xb, invvnU, es, sc,
                 O, nu, 10, 10, tid, h, g, kp, act, t0);
  // --- stage 2: m2 = |2-tap <v1, m1>|^2 * iv -> xb[1100..2200) ---
  do_stage<1, 2>(bufR, bufI, glr, gli, mkr, mki,
                 xb, xb, xb + 1100, invvnU, es, sc,
                 O, nu, 10, 9, tid, h, g, kp, act, t0);
  // --- stage 3: y3 = <u, m2> raw -> xb[0..2000) as [10][100] float2 ---
  do_stage<1, 3>(bufR, bufI, glr, gli, nullptr, nullptr,
                 xb + 1100, xb + 1100, xb, invvnU, es, sc,
                 O, nu, 9, 9, tid, h, g, kp, act, t0);

  // --- final: 3-tap window, |.|^2, * wn[t] * invvnU; sum over tile ---
  if (tid < KK) {
    const float2* y3f = (const float2*)xb;
    const int k = tid;
    const float iE = 1.f / sc[0], iZ1 = 1.f / sc[1], iZ2 = 1.f / sc[2];
    float acc = 0.f;
#pragma unroll
    for (int p = 0; p < T_TILE; ++p) {
      const int t = t0 + p;
      const float w0 = es[t] * iE;
      const float w1 = es[t + 1] * iZ1;
      const float w2 = es[t + 2] * iZ2;
      const float2 a = y3f[p * DD + k], bb = y3f[(p + 1) * DD + k],
                   c = y3f[(p + 2) * DD + k];
      const float qr = w0 * a.x + w1 * bb.x + w2 * c.x;
      const float qi = w0 * a.y + w1 * bb.y + w2 * c.y;
      acc += wnl[t] * (qr * qr + qi * qi);
    }
    partg[bt * KK + k] = acc * invvnU[k];
  }
}

// ---------------------------------------------------------------------------
__global__ __launch_bounds__(128) void k_out(
    const float* __restrict__ partg, const float* __restrict__ dw,
    const float* __restrict__ db, float* __restrict__ out)
{
  __shared__ float pr[KK];
  const int b = blockIdx.x, tid = threadIdx.x;
  if (tid < KK) {
    float s = 0.f;
#pragma unroll
    for (int q = 0; q < NTILES; ++q) s += partg[(b * NTILES + q) * KK + tid];
    pr[tid] = s;
  }
  __syncthreads();
  if (tid < 2) {
    float s = db[tid];
    for (int k = 0; k < KK; ++k) s += pr[k] * dw[k * 2 + tid];
    out[b * 2 + tid] = s;
  }
}

// ---------------------------------------------------------------------------
extern "C" void kernel_launch(void* const* d_in, const int* in_sizes, int n_in,
                              void* d_out, int out_size, void* d_ws, size_t ws_size,
                              hipStream_t stream) {
  const int*   seq  = (const int*)d_in[0];
  const float* ampT = (const float*)d_in[1];
  const float* phT  = (const float*)d_in[2];
  const float* pkr  = (const float*)d_in[3];
  const float* pki  = (const float*)d_in[4];
  const float* mkr  = (const float*)d_in[5];
  const float* mki  = (const float*)d_in[6];
  const float* dw   = (const float*)d_in[7];
  const float* db   = (const float*)d_in[8];
  float* out = (float*)d_out;

  float* ws    = (float*)d_ws;
  float* phR   = ws;                      // [2048][100]
  float* phI   = ws + 204800;             // [2048][100]
  float* es_g  = ws + 409600;             // [2048]
  float* wnl_g = ws + 411648;             // [2048]
  float* partg = ws + 413696;             // [256][100]

  k_phi  <<<32,           512, 0, stream>>>(seq, ampT, phT, phR, phI, es_g, wnl_g);
  k_fused<<<NB * NTILES,  NT,  0, stream>>>(phR, phI, es_g, wnl_g,
                                            pkr, pki, mkr, mki, partg);
  k_out  <<<NB,           128, 0, stream>>>(partg, dw, db, out);
}

// Round 10
// 68.591 us; speedup vs baseline: 2.7151x; 2.7151x over previous
//
#include <hip/hip_runtime.h>
#include <math.h>

// Problem constants: V=50000, D=100, B=16, S=128, U=100, L=2
#define NB 16
#define SS 128
#define DD 100
#define KK 100
#define T_TILE 8
#define NTILES 16
#define NT 768    // 12 waves = 6 pos-pairs (g) x 2 d-halves (h)

__device__ __forceinline__ float dot4(const float4 a, const float4 b) {
  return a.x * b.x + a.y * b.y + a.z * b.z + a.w * b.w;
}

// ---------------------------------------------------------------------------
// V staging: chunk c = 1000 granules (2 parts x 5 f4-rows x 100 k) = 16 KB.
// Global pattern: R3's proven one (k fastest -> stride-DD lanes).
// LDS layout: [part][j][(k&1)*50 + (k>>1)] -> conflict-free write AND read.
// ---------------------------------------------------------------------------
__device__ __forceinline__ void vload(const float* __restrict__ gr,
                                      const float* __restrict__ gi,
                                      int c, int tid, float4 (&pv)[2]) {
#pragma unroll
  for (int i = 0; i < 2; ++i) {
    const int e = tid + i * NT;
    if (e < 1000) {
      const int part = e / 500;
      const int rm = e - part * 500;
      const int j = rm / 100;
      const int k = rm - j * 100;
      pv[i] = *(const float4*)((part ? gi : gr) + k * DD + 4 * (5 * c + j));
    }
  }
}
__device__ __forceinline__ void vstore(float4* __restrict__ dst, int tid,
                                       const float4 (&pv)[2]) {
#pragma unroll
  for (int i = 0; i < 2; ++i) {
    const int e = tid + i * NT;
    if (e < 1000) {
      const int part = e / 500;
      const int rm = e - part * 500;
      const int j = rm / 100;
      const int k = rm - j * 100;
      dst[part * 500 + j * 100 + (k & 1) * 50 + (k >> 1)] = pv[i];
    }
  }
}

// ---------------------------------------------------------------------------
// One projection stage. MODE 0: complex x; MODE 1: real x.
// CM 1: m = |Y|^2*iv ; CM 2: m = |w0 Y(p)+w1 Y(p+1)|^2*iv ; CM 3: y3 = Y raw.
// Wave (h,g): d-half h (rows {0,1,2}/{3,4} of each chunk), positions 2g,2g+1.
// Lane kp owns k-pair (2kp,2kp+1). V filled LDS->VGPR per (chunk,j), FMA'd
// across 2 positions; x is a wave-uniform LDS broadcast. Partials [2][11][50]
// overlay the staging buffer; 2-way combine by h==0 waves.
// On entry pv holds this stage's chunk 0; on exit pv holds gnR's chunk 0.
// ---------------------------------------------------------------------------
template<int MODE, int CM>
__device__ __forceinline__ void do_stage(
    const float* __restrict__ gvr, const float* __restrict__ gvi,
    const float* __restrict__ gnR, const float* __restrict__ gnI,
    float4* __restrict__ vt, float4 (&pv)[2],
    const float4* __restrict__ xR4, const float4* __restrict__ xI4,
    float* __restrict__ outp, float* __restrict__ invvnU,
    const float* __restrict__ es, const float* __restrict__ sc,
    int pmaxF, int pmaxC,
    int tid, int h, int g, int kp, bool act, int t0)
{
  float ar[2][2] = {{0.f,0.f},{0.f,0.f}};
  float ai[2][2] = {{0.f,0.f},{0.f,0.f}};
  float n0 = 0.f, n1 = 0.f;
  const int p0 = 2 * g;
  const bool any = (p0 <= pmaxF);
  const int nj = (h == 0) ? 3 : 2;
  const int j0 = (h == 0) ? 0 : 3;

  vstore(vt, tid, pv);            // chunk 0 -> buf 0
  __syncthreads();

  for (int c = 0; c < 5; ++c) {
    if (c < 4)    vload(gvr, gvi, c + 1, tid, pv);     // prefetch 1 chunk ahead
    else if (gnR) vload(gnR, gnI, 0, tid, pv);         // next stage's chunk 0
    const float4* vb = vt + (c & 1) * 1000;
    if (any) {
#pragma unroll
      for (int jj = 0; jj < 3; ++jj) if (jj < nj) {
        const int j = j0 + jj;
        const float4 Vr0 = vb[j * 100 + kp];
        const float4 Vr1 = vb[j * 100 + 50 + kp];
        const float4 Vi0 = vb[500 + j * 100 + kp];
        const float4 Vi1 = vb[500 + j * 100 + 50 + kp];
        n0 += dot4(Vr0, Vr0) + dot4(Vi0, Vi0);
        n1 += dot4(Vr1, Vr1) + dot4(Vi1, Vi1);
        const int J = 5 * c + j;
#pragma unroll
        for (int e = 0; e < 2; ++e) {
          const int p = p0 + e;
          if (p <= pmaxF) {
            const float4 xr = xR4[p * 25 + J];
            if (MODE == 0) {
              const float4 xi = xI4[p * 25 + J];
              ar[e][0] += dot4(Vr0, xr) + dot4(Vi0, xi);
              ai[e][0] += dot4(Vr0, xi) - dot4(Vi0, xr);
              ar[e][1] += dot4(Vr1, xr) + dot4(Vi1, xi);
              ai[e][1] += dot4(Vr1, xi) - dot4(Vi1, xr);
            } else {
              ar[e][0] += dot4(Vr0, xr);
              ai[e][0] += dot4(Vi0, xr);
              ar[e][1] += dot4(Vr1, xr);
              ai[e][1] += dot4(Vi1, xr);
            }
          }
        }
      }
    }
    if (c < 4) vstore(vt + ((c + 1) & 1) * 1000, tid, pv);
    __syncthreads();
  }

  // partials overlay the (now dead) staging buffer
  float4* partlp = vt;                       // [2][11][50]
  float2* nrmhp  = (float2*)(vt + 1100);     // [2][50]
  if (act) {
#pragma unroll
    for (int e = 0; e < 2; ++e) {
      const int p = p0 + e;
      if (p <= pmaxF)
        partlp[(h * 11 + p) * 50 + kp] =
            make_float4(ar[e][0], ai[e][0], ar[e][1], ai[e][1]);
    }
    if (g == 0) nrmhp[h * 50 + kp] = make_float2(n0, n1);
  }
  __syncthreads();

  if (h == 0 && act) {
    const float2 q0 = nrmhp[kp], q1 = nrmhp[50 + kp];
    const float iv0 = 1.f / (q0.x + q1.x);
    const float iv1 = 1.f / (q0.y + q1.y);
#pragma unroll
    for (int e = 0; e < 2; ++e) {
      const int p = p0 + e;
      if (p <= pmaxC) {
        float4 s = partlp[p * 50 + kp];
        {
          const float4 b1 = partlp[(11 + p) * 50 + kp];
          s.x += b1.x; s.y += b1.y; s.z += b1.z; s.w += b1.w;
        }
        if (CM == 1) {
          *(float2*)(outp + p * DD + 2 * kp) =
              make_float2((s.x * s.x + s.y * s.y) * iv0,
                          (s.z * s.z + s.w * s.w) * iv1);
        } else if (CM == 2) {
          float4 u = partlp[(p + 1) * 50 + kp];
          const float4 c1 = partlp[(12 + p) * 50 + kp];
          u.x += c1.x; u.y += c1.y; u.z += c1.z; u.w += c1.w;
          const int t = t0 + p;
          const float w0 = es[t] / sc[0];
          const float w1 = es[t + 1] / sc[1];      // es zero-padded past SS
          const float r0 = w0 * s.x + w1 * u.x, i0 = w0 * s.y + w1 * u.y;
          const float r1 = w0 * s.z + w1 * u.z, i1 = w0 * s.w + w1 * u.w;
          *(float2*)(outp + p * DD + 2 * kp) =
              make_float2((r0 * r0 + i0 * i0) * iv0, (r1 * r1 + i1 * i1) * iv1);
        } else {
          *(float4*)(outp + p * 2 * DD + 4 * kp) = s;   // y3 [p][k] float2
        }
      }
    }
    if (CM == 3 && g == 0) { invvnU[2 * kp] = iv0; invvnU[2 * kp + 1] = iv1; }
  }
  __syncthreads();
}

// ---------------------------------------------------------------------------
__global__ __launch_bounds__(NT) void k_fused(
    const int* __restrict__ seq,
    const float* __restrict__ ampT, const float* __restrict__ phT,
    const float* __restrict__ pkr, const float* __restrict__ pki,
    const float* __restrict__ mkr, const float* __restrict__ mki,
    float* __restrict__ partg)
{
  __shared__ __align__(16) float4 vt[2000];   // 32 KB staging / partials union
  __shared__ __align__(16) float xb[2208];    // phi_r|phi_i -> m1|m2 -> y3
  __shared__ float es[SS + 8], wnl[SS], invvnU[KK], sc[3], redw[2];

  const int tid  = threadIdx.x;
  const int lane = tid & 63;
  const int wid  = tid >> 6;      // 0..11
  const int h    = wid & 1;       // d-half
  const int g    = wid >> 1;      // pos-pair (0..5)
  const bool act = lane < 50;
  const int kp   = act ? lane : 49;
  const int bt   = blockIdx.x;
  const int b    = bt >> 4;
  const int t0   = (bt & 15) * T_TILE;
  const int sb   = b * SS;

  float4 pv[2];
  vload(pkr, pki, 0, tid, pv);    // stage-1 chunk 0, issued first

  // --- prologue A: ||amp|| + exp for all 128 positions of batch b ---
  if (tid < 512) {
    const int t = tid >> 2, qq = tid & 3;
    const int row = seq[sb + t];
    const float* ap = ampT + (long)row * DD;
    float s = 0.f;
#pragma unroll
    for (int i = 0; i < 7; ++i) {
      const int j = qq + 4 * i;
      if (j < 25) {
        const float4 a4 = *(const float4*)(ap + 4 * j);
        s += dot4(a4, a4);
      }
    }
    s += __shfl_xor(s, 1);
    s += __shfl_xor(s, 2);
    if (qq == 0) { const float n = sqrtf(s); wnl[t] = n; es[t] = expf(n); }
  }
  if (tid >= NT - 8) es[SS + tid - (NT - 8)] = 0.f;
  __syncthreads();

  // --- prologue B: E-reduce + phi halo -> LDS ---
  if (tid < SS) {
    float v = es[tid];
#pragma unroll
    for (int m = 32; m; m >>= 1) v += __shfl_xor(v, m);
    if ((tid & 63) == 0) redw[tid >> 6] = v;
  }
#pragma unroll
  for (int r = 0; r < 2; ++r) {
    const int e2 = tid + NT * r;
    if (e2 < 11 * DD) {
      const int p = e2 / DD, d = e2 - p * DD;
      const int t = t0 + p;
      float pr = 0.f, pi = 0.f;
      if (t < SS) {
        const int row = seq[sb + t];
        const float a  = ampT[(long)row * DD + d];
        const float ph = phT[(long)row * DD + d];
        float sv, cv; sincosf(ph, &sv, &cv);
        const float an = a / wnl[t];
        pr = an * cv; pi = an * sv;
      }
      xb[e2]        = pr;
      xb[1100 + e2] = pi;
    }
  }
  __syncthreads();
  if (tid == 0) {
    const float E = redw[0] + redw[1];
    sc[0] = E; sc[1] = E - es[0] + 1.f; sc[2] = E - es[0] - es[1] + 2.f;
  }
  // sc first consumed at stage-2 combine (many barriers later)

  // --- stage 1: m1 = |<v0, phi>|^2 * iv  -> xb[0..1100) ---
  do_stage<0, 1>(pkr, pki, pkr + DD * DD, pki + DD * DD, vt, pv,
                 (const float4*)xb, (const float4*)(xb + 1100),
                 xb, invvnU, es, sc, 10, 10, tid, h, g, kp, act, t0);
  // --- stage 2: m2 = |2-tap <v1, m1>|^2 * iv -> xb[1100..2200) ---
  do_stage<1, 2>(pkr + DD * DD, pki + DD * DD, mkr, mki, vt, pv,
                 (const float4*)xb, (const float4*)xb,
                 xb + 1100, invvnU, es, sc, 10, 9, tid, h, g, kp, act, t0);
  // --- stage 3: y3 = <u, m2> raw -> xb[0..2000) as [10][100] float2 ---
  do_stage<1, 3>(mkr, mki, nullptr, nullptr, vt, pv,
                 (const float4*)(xb + 1100), (const float4*)(xb + 1100),
                 xb, invvnU, es, sc, 9, 9, tid, h, g, kp, act, t0);

  // --- final: 3-tap window, |.|^2, * wn[t] * invvnU; sum over tile ---
  if (tid < KK) {
    const float2* y3f = (const float2*)xb;
    const int k = tid;
    const float iE = 1.f / sc[0], iZ1 = 1.f / sc[1], iZ2 = 1.f / sc[2];
    float acc = 0.f;
#pragma unroll
    for (int p = 0; p < T_TILE; ++p) {
      const int t = t0 + p;
      const float w0 = es[t] * iE;
      const float w1 = es[t + 1] * iZ1;
      const float w2 = es[t + 2] * iZ2;
      const float2 a = y3f[p * DD + k], bb = y3f[(p + 1) * DD + k],
                   c = y3f[(p + 2) * DD + k];
      const float qr = w0 * a.x + w1 * bb.x + w2 * c.x;
      const float qi = w0 * a.y + w1 * bb.y + w2 * c.y;
      acc += wnl[t] * (qr * qr + qi * qi);
    }
    partg[bt * KK + k] = acc * invvnU[k];
  }
}

// ---------------------------------------------------------------------------
__global__ __launch_bounds__(128) void k_out(
    const float* __restrict__ partg, const float* __restrict__ dw,
    const float* __restrict__ db, float* __restrict__ out)
{
  __shared__ float pr[KK];
  const int b = blockIdx.x, tid = threadIdx.x;
  if (tid < KK) {
    float s = 0.f;
#pragma unroll
    for (int q = 0; q < NTILES; ++q) s += partg[(b * NTILES + q) * KK + tid];
    pr[tid] = s;
  }
  __syncthreads();
  if (tid < 2) {
    float s = db[tid];
    for (int k = 0; k < KK; ++k) s += pr[k] * dw[k * 2 + tid];
    out[b * 2 + tid] = s;
  }
}

// ---------------------------------------------------------------------------
extern "C" void kernel_launch(void* const* d_in, const int* in_sizes, int n_in,
                              void* d_out, int out_size, void* d_ws, size_t ws_size,
                              hipStream_t stream) {
  const int*   seq  = (const int*)d_in[0];
  const float* ampT = (const float*)d_in[1];
  const float* phT  = (const float*)d_in[2];
  const float* pkr  = (const float*)d_in[3];
  const float* pki  = (const float*)d_in[4];
  const float* mkr  = (const float*)d_in[5];
  const float* mki  = (const float*)d_in[6];
  const float* dw   = (const float*)d_in[7];
  const float* db   = (const float*)d_in[8];
  float* out   = (float*)d_out;
  float* partg = (float*)d_ws;    // [256][100] floats, only global scratch

  k_fused<<<NB * NTILES, NT, 0, stream>>>(seq, ampT, phT, pkr, pki, mkr, mki, partg);
  k_out  <<<NB,          128, 0, stream>>>(partg, dw, db, out);
}

// Round 11
// 33.899 us; speedup vs baseline: 5.4937x; 2.0234x over previous
//
#include <hip/hip_runtime.h>
#include <math.h>

// Problem constants: V=50000, D=100, B=16, S=128, U=100, L=2
#define NB 16
#define SS 128
#define DD 100
#define KK 100
#define T_TILE 8            // output positions per block
#define P_HALO 11           // T_TILE + 3 (dependency cone)
#define NTILES 16           // SS / T_TILE
#define NT 768              // threads per block (12 waves, 3/SIMD)
#define NWAVES 12
#define CH_D4 5             // d4-rows per chunk
#define NCHUNK 5            // 25 d4-rows total (D=100)

__device__ __forceinline__ float dot4(const float4 a, const float4 b) {
  return a.x * b.x + a.y * b.y + a.z * b.z + a.w * b.w;
}

// ---------------------------------------------------------------------------
// Per-chunk accumulate for BOTH of a wave's slots (same k-half -> V fragments
// read ONCE and reused; explicit CSE of the champion's two accum_slot calls).
// MODE 0: complex x (stage 1).  MODE 1: real x (stages 2, 3).
// ---------------------------------------------------------------------------
template<int MODE>
__device__ __forceinline__ void accum_pair(
    const float4* __restrict__ vtb,
    const float4 (*__restrict__ bxr)[25], const float4 (*__restrict__ bxi)[25],
    int p0, int p1, bool a0, bool a1, int k, int c,
    float& r0a, float& i0a, float& r1a, float& i1a)
{
#pragma unroll
  for (int r = 0; r < CH_D4; ++r) {
    const int d4 = c * CH_D4 + r;
    const float4 vr4 = vtb[r * KK + k];          // read once,
    const float4 vi4 = vtb[500 + r * KK + k];    // used by both slots
    if (a0) {
      const float4 x4 = bxr[p0][d4];
      if (MODE == 0) {
        const float4 z4 = bxi[p0][d4];
        r0a += dot4(vr4, x4) + dot4(vi4, z4);
        i0a += dot4(vr4, z4) - dot4(vi4, x4);
      } else {
        r0a += dot4(vr4, x4);
        i0a += dot4(vi4, x4);
      }
    }
    if (a1) {
      const float4 x4 = bxr[p1][d4];
      if (MODE == 0) {
        const float4 z4 = bxi[p1][d4];
        r1a += dot4(vr4, x4) + dot4(vi4, z4);
        i1a += dot4(vr4, z4) - dot4(vi4, x4);
      } else {
        r1a += dot4(vr4, x4);
        i1a += dot4(vi4, x4);
      }
    }
  }
}

// ---------------------------------------------------------------------------
// One projection stage: row-norm pass, chunked double-buffered transpose of
// the 100x100 complex matrix into LDS, dot products for all slots.
// MODE 0: writes m[p][k] = (ar^2+ai^2)*invvn[k].  MODE 1: writes y2 = (ar,ai).
// Caller must __syncthreads() after return before consuming outputs.
// ---------------------------------------------------------------------------
template<int MODE>
__device__ __forceinline__ void run_stage(
    const float* __restrict__ gvr, const float* __restrict__ gvi,
    float4 (*__restrict__ vt)[1000],
    const float4 (*__restrict__ bxr)[25], const float4 (*__restrict__ bxi)[25],
    float* __restrict__ mflat, float2* __restrict__ y2flat,
    float* __restrict__ invvn, const int nslots,
    const int tid, const int lane, const int wid)
{
  // --- row norms of this stage's matrix (4 lanes per row) ---
  if (tid < 4 * KK) {
    const int k = tid >> 2, q = tid & 3;
    const float* r0 = gvr + k * DD + q;
    const float* i0 = gvi + k * DD + q;
    float s = 0.f;
#pragma unroll
    for (int i = 0; i < 25; ++i) { const float a = r0[4*i], c2 = i0[4*i]; s += a*a + c2*c2; }
    s += __shfl_xor(s, 1, 64);
    s += __shfl_xor(s, 2, 64);
    if (q == 0) invvn[k] = 1.0f / s;
  }

  // element e of a chunk: part=e/500, r=(e%500)/100, k=e%100
  // global source: gv_part + k*DD + 4*(c*CH_D4 + r)   (16B aligned)
  const int e0 = tid;                 // always < 1000
  const int e1 = tid + NT;            // valid for tid < 232
  const int p0 = e0 / 500, rm0 = e0 % 500, r0_ = rm0 / 100, k0_ = rm0 % 100;
  const int p1 = e1 / 500, rm1 = e1 % 500, r1_ = rm1 / 100, k1_ = rm1 % 100;
  const float* g0 = (p0 ? gvi : gvr) + k0_ * DD + 4 * r0_;
  const float* g1 = (p1 ? gvi : gvr) + k1_ * DD + 4 * r1_;

  float4 pv0, pv1;
  pv0 = *(const float4*)(g0);                      // chunk 0
  if (e1 < 1000) pv1 = *(const float4*)(g1);
  vt[0][e0] = pv0;
  if (e1 < 1000) vt[0][e1] = pv1;
  __syncthreads();

  const int s0 = wid, s1 = wid + NWAVES;
  float a0r = 0.f, a0i = 0.f, a1r = 0.f, a1i = 0.f;
  const int kk = (s0 & 1) * 50 + lane;     // s0 and s1 share parity -> same k
  const int pp0 = s0 >> 1, pp1 = s1 >> 1;
  const bool act0 = (s0 < nslots), act1 = (s1 < nslots);

  for (int c = 0; c < NCHUNK; ++c) {
    const int buf = c & 1;
    if (c + 1 < NCHUNK) {                           // issue next-chunk loads early
      pv0 = *(const float4*)(g0 + 4 * CH_D4 * (c + 1));
      if (e1 < 1000) pv1 = *(const float4*)(g1 + 4 * CH_D4 * (c + 1));
    }
    if (lane < 50)
      accum_pair<MODE>(vt[buf], bxr, bxi, pp0, pp1, act0, act1, kk, c,
                       a0r, a0i, a1r, a1i);
    if (c + 1 < NCHUNK) {                           // write-late into other buffer
      const int nb = buf ^ 1;
      vt[nb][e0] = pv0;
      if (e1 < 1000) vt[nb][e1] = pv1;
    }
    __syncthreads();
  }

  if (lane < 50) {
    if (act0) {
      if (MODE == 0) mflat[pp0 * KK + kk] = (a0r * a0r + a0i * a0i) * invvn[kk];
      else           y2flat[pp0 * KK + kk] = make_float2(a0r, a0i);
    }
    if (act1) {
      if (MODE == 0) mflat[pp1 * KK + kk] = (a1r * a1r + a1i * a1i) * invvn[kk];
      else           y2flat[pp1 * KK + kk] = make_float2(a1r, a1i);
    }
  }
}

// ---------------------------------------------------------------------------
// Fused kernel: block = (batch, tile of 8 positions). Computes the full
// 3-stage pipeline for its halo cone (11 positions) and writes partial probs.
// ---------------------------------------------------------------------------
__global__ __launch_bounds__(NT) void k_fused(
    const int* __restrict__ seq,
    const float* __restrict__ ampT, const float* __restrict__ phT,
    const float* __restrict__ pkr, const float* __restrict__ pki,
    const float* __restrict__ mkr, const float* __restrict__ mki,
    float* __restrict__ part)
{
  __shared__ float4 vt[2][1000];        // 32000 B: V chunk double-buffer
  __shared__ float4 xr4[P_HALO][25];    // stage-1 phi real
  __shared__ float4 xi4[P_HALO][25];    // stage-1 phi imag
  __shared__ float4 m4[P_HALO][25];     // m vector (m1, then m2, then scratch)
  __shared__ float2 y2[P_HALO][KK];     // projection pair outputs
  __shared__ float es[SS];
  __shared__ float wnl[SS];
  __shared__ float invvn[KK];
  __shared__ float redw[NWAVES];
  __shared__ float sc[3];               // E, Z1, Z2

  const int tid  = threadIdx.x;
  const int lane = tid & 63;
  const int wid  = tid >> 6;
  const int bt   = blockIdx.x;
  const int b    = bt >> 4;
  const int tile = bt & 15;
  const int t0   = tile * T_TILE;
  const int sb   = b * SS;

  // --- prologue A: norms + exp for ALL 128 positions of this batch ---
  if (tid < 4 * SS) {                   // waves 0..7 exactly
    const int t = tid >> 2, q = tid & 3;
    const int row = seq[sb + t];
    const float* ap = ampT + (long)row * DD + q;
    float s = 0.f;
#pragma unroll
    for (int i = 0; i < 25; ++i) { const float a = ap[4*i]; s += a * a; }
    s += __shfl_xor(s, 1, 64);
    s += __shfl_xor(s, 2, 64);
    if (q == 0) { const float nrm = sqrtf(s); wnl[t] = nrm; es[t] = expf(nrm); }
  }
  __syncthreads();

  // --- E and closed-form softmax denominators ---
  {
    float v = (tid < SS) ? es[tid] : 0.f;
    for (int m = 32; m; m >>= 1) v += __shfl_xor(v, m, 64);
    if (lane == 0) redw[wid] = v;
  }
  // --- prologue B: phi = (amp/||amp||) * e^{i phase} for halo positions ---
  for (int idx = tid; idx < P_HALO * 25; idx += NT) {
    const int p = idx / 25, d4 = idx % 25;
    const int tp = t0 + p;
    float4 o_r = {0.f, 0.f, 0.f, 0.f}, o_i = {0.f, 0.f, 0.f, 0.f};
    if (tp < SS) {
      const int row = seq[sb + tp];
      const float4 a4 = *(const float4*)(ampT + (long)row * DD + 4 * d4);
      const float4 p4 = *(const float4*)(phT  + (long)row * DD + 4 * d4);
      const float inv = 1.0f / wnl[tp];
      float sv, cv;
      sincosf(p4.x, &sv, &cv); o_r.x = a4.x * inv * cv; o_i.x = a4.x * inv * sv;
      sincosf(p4.y, &sv, &cv); o_r.y = a4.y * inv * cv; o_i.y = a4.y * inv * sv;
      sincosf(p4.z, &sv, &cv); o_r.z = a4.z * inv * cv; o_i.z = a4.z * inv * sv;
      sincosf(p4.w, &sv, &cv); o_r.w = a4.w * inv * cv; o_i.w = a4.w * inv * sv;
    }
    xr4[p][d4] = o_r;
    xi4[p][d4] = o_i;
  }
  __syncthreads();
  if (tid == 0) {
    float E = 0.f;
    for (int w = 0; w < NWAVES; ++w) E += redw[w];
    sc[0] = E;
    sc[1] = E - es[0] + 1.0f;
    sc[2] = E - es[0] - es[1] + 2.0f;
  }
  __syncthreads();

  // --- stage 1: m1[p][k] = |<v0_k, phi_p>|^2 / ||v0_k||^2 ---
  run_stage<0>(pkr, pki, vt, xr4, xi4, (float*)m4, nullptr, invvn,
               2 * P_HALO, tid, lane, wid);
  __syncthreads();

  // --- stage 2: y2[p][k] = (sum vr*m1, sum vi*m1) for proj layer 1 ---
  run_stage<1>(pkr + DD * DD, pki + DD * DD, vt, m4, m4, nullptr,
               (float2*)y2, invvn, 2 * P_HALO, tid, lane, wid);
  __syncthreads();

  // --- m2 = 2-tap window of y2, squared, scaled by invvn (layer-1 norms) ---
  {
    const float E = sc[0], Z1 = sc[1];
    for (int idx = tid; idx < 10 * KK; idx += NT) {
      const int p = idx / KK, k = idx - p * KK;
      const int t = t0 + p;
      const float w0 = ((t     < SS) ? es[t]     : 1.f) / E;
      const float w1 = ((t + 1 < SS) ? es[t + 1] : 1.f) / Z1;
      const float2 ya = y2[p][k], yb = y2[p + 1][k];
      const float ar = w0 * ya.x + w1 * yb.x;
      const float ai = w0 * ya.y + w1 * yb.y;
      ((float*)m4)[p * KK + k] = (ar * ar + ai * ai) * invvn[k];
    }
  }
  __syncthreads();

  // --- stage 3: y2[p][k] = (sum ur*m2, sum ui*m2), p < 10 ---
  run_stage<1>(mkr, mki, vt, m4, m4, nullptr,
               (float2*)y2, invvn, 20, tid, lane, wid);
  __syncthreads();

  // --- final: 3-tap window, square, * wn[t] * invvn_U[k]; sum over own p ---
  {
    const float E = sc[0], Z1 = sc[1], Z2 = sc[2];
    for (int idx = tid; idx < T_TILE * KK; idx += NT) {
      const int p = idx / KK, k = idx - p * KK;
      const int t = t0 + p;                         // < 128 always
      const float w0 = es[t] / E;
      const float w1 = ((t + 1 < SS) ? es[t + 1] : 1.f) / Z1;
      const float w2 = ((t + 2 < SS) ? es[t + 2] : 1.f) / Z2;
      const float2 ya = y2[p][k], yb = y2[p + 1][k], yc = y2[p + 2][k];
      const float qr = w0 * ya.x + w1 * yb.x + w2 * yc.x;
      const float qi = w0 * ya.y + w1 * yb.y + w2 * yc.y;
      ((float*)m4)[p * KK + k] = wnl[t] * (qr * qr + qi * qi) * invvn[k];
    }
  }
  __syncthreads();
  if (tid < KK) {
    float s = 0.f;
#pragma unroll
    for (int p = 0; p < T_TILE; ++p) s += ((float*)m4)[p * KK + tid];
    part[bt * KK + tid] = s;
  }
}

// ---------------------------------------------------------------------------
// Output: probs[b,k] = sum_tiles part; out = probs @ dense_w + dense_b
// ---------------------------------------------------------------------------
__global__ __launch_bounds__(128) void k_out(
    const float* __restrict__ part, const float* __restrict__ dw,
    const float* __restrict__ db, float* __restrict__ out)
{
  __shared__ float pr[KK];
  const int b = blockIdx.x, tid = threadIdx.x;
  if (tid < KK) {
    float s = 0.f;
#pragma unroll
    for (int q = 0; q < NTILES; ++q) s += part[(b * NTILES + q) * KK + tid];
    pr[tid] = s;
  }
  __syncthreads();
  if (tid < 2) {
    float s = db[tid];
    for (int k = 0; k < KK; ++k) s += pr[k] * dw[k * 2 + tid];
    out[b * 2 + tid] = s;
  }
}

// ---------------------------------------------------------------------------
extern "C" void kernel_launch(void* const* d_in, const int* in_sizes, int n_in,
                              void* d_out, int out_size, void* d_ws, size_t ws_size,
                              hipStream_t stream) {
  const int*   seq  = (const int*)d_in[0];
  const float* ampT = (const float*)d_in[1];
  const float* phT  = (const float*)d_in[2];
  const float* pkr  = (const float*)d_in[3];
  const float* pki  = (const float*)d_in[4];
  const float* mkr  = (const float*)d_in[5];
  const float* mki  = (const float*)d_in[6];
  const float* dw   = (const float*)d_in[7];
  const float* db   = (const float*)d_in[8];
  float* out  = (float*)d_out;
  float* part = (float*)d_ws;                 // 256*100 floats = 102.4 KB

  k_fused<<<NB * NTILES, NT, 0, stream>>>(seq, ampT, phT, pkr, pki, mkr, mki, part);
  k_out  <<<NB,          128, 0, stream>>>(part, dw, db, out);
}